// Round 4
// baseline (1218.073 us; speedup 1.0000x reference)
//
#include <hip/hip_runtime.h>

#define B_   2
#define D_   32
#define H_   256
#define W_   256
#define N_   150000
#define CIN  16
#define CMID 32
#define COUT 64
#define DO_  16
#define HO_  128
#define WO_  128
#define M_   (B_*DO_*HO_*WO_)   /* 524288 */
#define EPSf 1e-5f
#define NB_DOWN 8192             /* k_down blocks; %8==0, 32 vox-pairs per block */

// ---------------- grid scatter ----------------
__global__ __launch_bounds__(256) void k_scatter(const int* __restrict__ coords,
                                                 int* __restrict__ grid) {
    int i = blockIdx.x * 256 + threadIdx.x;
    if (i >= N_) return;
    const int4 c = *(const int4*)(coords + 4 * (size_t)i);
    grid[((c.x * D_ + c.y) * H_ + c.z) * W_ + c.w] = i;
}

// ---------------- weight transpose ----------------
// Wt1[ki][(q*2+hi)*32+co][j] = W1[ki][hi*8 +q*4+j][co]   (q<2)
// Wt2[ki][(q*2+hi)*32+co][j] = W2[ki][hi*16+q*4+j][co]   (q<4)
// Wt3[ki][ q*64      +co][j] = W3[ki][      q*4+j][co]   (q<8, co<64)
__global__ __launch_bounds__(256) void k_twist(const float* __restrict__ W1,
                                               const float* __restrict__ W2,
                                               const float* __restrict__ W3,
                                               float* __restrict__ Wt1,
                                               float* __restrict__ Wt2,
                                               float* __restrict__ Wt3) {
    const int t = blockIdx.x * 256 + threadIdx.x;
    if (t < 3456) {
        const int ki = t / 128, r = t % 128;
        const int co = r & 31, qh = r >> 5, hi = qh & 1, q = qh >> 1;
        const float* src = W1 + ki * 512 + (hi * 8 + q * 4) * 32 + co;
        float4 o; o.x = src[0]; o.y = src[32]; o.z = src[64]; o.w = src[96];
        ((float4*)Wt1)[t] = o;
    } else if (t < 3456 + 6912) {
        const int u = t - 3456;
        const int ki = u / 256, r = u % 256;
        const int co = r & 31, qh = r >> 5, hi = qh & 1, q = qh >> 1;
        const float* src = W2 + ki * 1024 + (hi * 16 + q * 4) * 32 + co;
        float4 o; o.x = src[0]; o.y = src[32]; o.z = src[64]; o.w = src[96];
        ((float4*)Wt2)[u] = o;
    } else if (t < 3456 + 6912 + 13824) {
        const int u = t - 3456 - 6912;
        const int ki = u / 512, r = u % 512;
        const int co = r & 63, q = r >> 6;
        const float* src = W3 + ki * 2048 + q * 4 * 64 + co;
        float4 o; o.x = src[0]; o.y = src[64]; o.z = src[128]; o.w = src[192];
        ((float4*)Wt3)[u] = o;
    }
}

// ---------------- submanifold conv: one wave per POINT-PAIR + fused stats ----
template <int CI>
__global__ __launch_bounds__(256) void k_subm(const float* __restrict__ X,
                                              const int* __restrict__ coords,
                                              const int* __restrict__ grid,
                                              const float* __restrict__ Wt,
                                              const float* __restrict__ bias,
                                              float* __restrict__ Y,
                                              float* __restrict__ stats) {
    const int pid  = (blockIdx.x * 256 + threadIdx.x) >> 6;
    const int lane = threadIdx.x & 63;
    const int sub  = lane & 31;
    const int half = lane >> 5;
    const int iA   = pid * 2;

    const int4 cA = *(const int4*)(coords + 4 * (size_t)iA);
    const int4 cB = *(const int4*)(coords + 4 * (size_t)(iA + 1));
    const int4 cc = half ? cB : cA;

    int nidx = -1;
    if (sub < 27) {
        const int nz = cc.y + sub / 9 - 1;
        const int ny = cc.z + (sub / 3) % 3 - 1;
        const int nx = cc.w + sub % 3 - 1;
        if ((unsigned)nz < (unsigned)D_ && (unsigned)ny < (unsigned)H_ &&
            (unsigned)nx < (unsigned)W_)
            nidx = grid[((cc.x * D_ + nz) * H_ + ny) * W_ + nx];
    }
    const unsigned long long act = __ballot(nidx >= 0);
    unsigned int actA = (unsigned int)(act & 0x7FFFFFFull);
    unsigned int actB = (unsigned int)((act >> 32) & 0x7FFFFFFull);

    float accA = 0.f, accB = 0.f;

    while (actA | actB) {
        if (actA) {
            const int ki = __builtin_ctz(actA); actA &= actA - 1;
            const int ni = __builtin_amdgcn_readfirstlane(__shfl(nidx, ki, 64));
            const float* __restrict__ f = X + (size_t)ni * CI + half * (CI / 2);
            const float4* __restrict__ w4 =
                (const float4*)Wt + (size_t)ki * (CI * 8) + half * 32 + sub;
#pragma unroll
            for (int q = 0; q < CI / 8; ++q) {
                const float4 fv = *(const float4*)(f + q * 4);
                const float4 wv = w4[q * 64];
                accA = fmaf(fv.x, wv.x, accA);
                accA = fmaf(fv.y, wv.y, accA);
                accA = fmaf(fv.z, wv.z, accA);
                accA = fmaf(fv.w, wv.w, accA);
            }
        }
        if (actB) {
            const int ki = __builtin_ctz(actB); actB &= actB - 1;
            const int ni = __builtin_amdgcn_readfirstlane(__shfl(nidx, ki + 32, 64));
            const float* __restrict__ f = X + (size_t)ni * CI + half * (CI / 2);
            const float4* __restrict__ w4 =
                (const float4*)Wt + (size_t)ki * (CI * 8) + half * 32 + sub;
#pragma unroll
            for (int q = 0; q < CI / 8; ++q) {
                const float4 fv = *(const float4*)(f + q * 4);
                const float4 wv = w4[q * 64];
                accB = fmaf(fv.x, wv.x, accB);
                accB = fmaf(fv.y, wv.y, accB);
                accB = fmaf(fv.z, wv.z, accB);
                accB = fmaf(fv.w, wv.w, accB);
            }
        }
    }

    accA += __shfl_xor(accA, 32, 64);     // combine ci halves
    accB += __shfl_xor(accB, 32, 64);
    const float outv = (half ? accB : accA) + bias[sub];
    Y[(size_t)(iA + half) * 32 + sub] = outv;

    // fused per-channel stats: channel = sub, 8 samples per block (4 waves x 2 pts)
    __shared__ float sd[256];
    const int tid = threadIdx.x;
    sd[tid] = outv;
    __syncthreads();
    if (tid < 32) {
        float s = 0.f;
#pragma unroll
        for (int k = 0; k < 8; ++k) s += sd[tid + 32 * k];
        atomicAdd(stats + tid, s);
    }
    __syncthreads();
    sd[tid] = outv * outv;
    __syncthreads();
    if (tid < 32) {
        float s = 0.f;
#pragma unroll
        for (int k = 0; k < 8; ++k) s += sd[tid + 32 * k];
        atomicAdd(stats + 32 + tid, s);
    }
}

// ---------------- strided down conv: wave per voxel-pair, pipelined probe ----
__global__ __launch_bounds__(256) void k_down(const float* __restrict__ X,
                                              const int* __restrict__ grid,
                                              const float* __restrict__ Wt3,
                                              const float* __restrict__ bias,
                                              float* __restrict__ Y,
                                              unsigned char* __restrict__ mask,
                                              float* __restrict__ stats,
                                              int* __restrict__ nact) {
    const int b    = blockIdx.x;
    const int swz  = (b & 7) * (NB_DOWN / 8) + (b >> 3);
    const int wv   = threadIdx.x >> 6;
    const int lane = threadIdx.x & 63;
    const int sub  = lane & 31;
    const int half = lane >> 5;

    const int vox0 = swz * 64;
    const int ox0  = vox0 & 127;
    int t = vox0 >> 7;
    const int oy = t & 127; t >>= 7;
    const int oz = t & 15;
    const int bb = t >> 4;

    const int dz = sub / 9, dy = (sub / 3) % 3, dx = sub % 3;
    const int z = 2 * oz - 1 + dz;
    const int y = 2 * oy - 1 + dy;
    const bool zyok = ((unsigned)z < (unsigned)D_) && ((unsigned)y < (unsigned)H_) && (sub < 27);
    const int rowbase = ((bb * D_ + (zyok ? z : 0)) * H_ + (zyok ? y : 0)) * W_;

    const float bv = bias[lane];
    float s = 0.f, s2 = 0.f;
    int cnt = 0;

    // prologue probe (it = 0)
    int nidx = -1;
    {
        const int ox = ox0 + (wv * 8) * 2 + half;
        const int x  = 2 * ox - 1 + dx;
        if (zyok && (unsigned)x < (unsigned)W_) nidx = grid[rowbase + x];
    }

    for (int it = 0; it < 8; ++it) {
        const unsigned long long act = __ballot(nidx >= 0);
        const int nidx_cur = nidx;

        // pipelined probe for it+1 (issues before the tap FMA chain)
        nidx = -1;
        if (it < 7) {
            const int ox = ox0 + (wv * 8 + it + 1) * 2 + half;
            const int x  = 2 * ox - 1 + dx;
            if (zyok && (unsigned)x < (unsigned)W_) nidx = grid[rowbase + x];
        }

        unsigned int actA = (unsigned int)(act & 0x7FFFFFFull);
        unsigned int actB = (unsigned int)((act >> 32) & 0x7FFFFFFull);
        const int mkA = actA ? 1 : 0;
        const int mkB = actB ? 1 : 0;

        float accA = 0.f, accB = 0.f;
        while (actA | actB) {
            if (actA) {
                const int ki = __builtin_ctz(actA); actA &= actA - 1;
                const int ni = __builtin_amdgcn_readfirstlane(__shfl(nidx_cur, ki, 64));
                const float* __restrict__ fS = X + (size_t)ni * CMID;   // SGPR base
                const float4* __restrict__ w4 = (const float4*)Wt3 + (size_t)ki * 512 + lane;
#pragma unroll
                for (int q = 0; q < 8; ++q) {
                    const float4 wv4 = w4[q * 64];
                    accA = fmaf(fS[4 * q + 0], wv4.x, accA);
                    accA = fmaf(fS[4 * q + 1], wv4.y, accA);
                    accA = fmaf(fS[4 * q + 2], wv4.z, accA);
                    accA = fmaf(fS[4 * q + 3], wv4.w, accA);
                }
            }
            if (actB) {
                const int ki = __builtin_ctz(actB); actB &= actB - 1;
                const int ni = __builtin_amdgcn_readfirstlane(__shfl(nidx_cur, ki + 32, 64));
                const float* __restrict__ fS = X + (size_t)ni * CMID;
                const float4* __restrict__ w4 = (const float4*)Wt3 + (size_t)ki * 512 + lane;
#pragma unroll
                for (int q = 0; q < 8; ++q) {
                    const float4 wv4 = w4[q * 64];
                    accB = fmaf(fS[4 * q + 0], wv4.x, accB);
                    accB = fmaf(fS[4 * q + 1], wv4.y, accB);
                    accB = fmaf(fS[4 * q + 2], wv4.z, accB);
                    accB = fmaf(fS[4 * q + 3], wv4.w, accB);
                }
            }
        }

        const int pr = wv * 8 + it;
        const int vA = vox0 + pr * 2;
        const float oA = mkA ? accA + bv : 0.f;
        const float oB = mkB ? accB + bv : 0.f;
        Y[(size_t)vA * COUT + lane]       = oA;
        Y[(size_t)(vA + 1) * COUT + lane] = oB;
        if (lane == 0) {
            mask[vA]     = (unsigned char)mkA;
            mask[vA + 1] = (unsigned char)mkB;
            cnt += mkA + mkB;
        }
        s  += oA + oB;
        s2 += oA * oA + oB * oB;
    }

    __shared__ float sd[256];
    __shared__ int   scnt[4];
    const int tid = threadIdx.x;
    sd[tid] = s;
    if (lane == 0) scnt[wv] = cnt;
    __syncthreads();
    if (tid < 64) atomicAdd(stats + tid, sd[tid] + sd[tid + 64] + sd[tid + 128] + sd[tid + 192]);
    __syncthreads();
    sd[tid] = s2;
    __syncthreads();
    if (tid < 64) atomicAdd(stats + 64 + tid, sd[tid] + sd[tid + 64] + sd[tid + 128] + sd[tid + 192]);
    if (tid == 0) atomicAdd(nact, scnt[0] + scnt[1] + scnt[2] + scnt[3]);
}

// ---------------- finalize scale/shift ----------------
template <int C>
__global__ void k_finstats(const float* __restrict__ stats,
                           const float* __restrict__ g,
                           const float* __restrict__ be,
                           float nfix, const int* __restrict__ nact,
                           float* __restrict__ ss) {
    const int c = threadIdx.x;
    if (c >= C) return;
    float n = nfix;
    if (nact) { int na = *nact; n = (float)(na > 0 ? na : 1); }
    const float m  = stats[c] / n;
    const float v  = stats[C + c] / n - m * m;
    const float sc = g[c] * rsqrtf(v + EPSf);
    ss[c]     = sc;
    ss[C + c] = be[c] - m * sc;
}

// ---------------- normalize (BN+ReLU) ----------------
template <int C>
__global__ __launch_bounds__(256) void k_norm(const float* __restrict__ Y,
                                              const float* __restrict__ ss,
                                              float* __restrict__ Xo, long n4) {
    const long t = (long)blockIdx.x * 256 + threadIdx.x;
    if (t >= n4) return;
    const float4 y = ((const float4*)Y)[t];
    const int ch = (int)((t * 4) % C);
    float4 o;
    o.x = fmaxf(fmaf(y.x, ss[ch],     ss[C + ch]),     0.f);
    o.y = fmaxf(fmaf(y.y, ss[ch + 1], ss[C + ch + 1]), 0.f);
    o.z = fmaxf(fmaf(y.z, ss[ch + 2], ss[C + ch + 2]), 0.f);
    o.w = fmaxf(fmaf(y.w, ss[ch + 3], ss[C + ch + 3]), 0.f);
    ((float4*)Xo)[t] = o;
}

__global__ __launch_bounds__(256) void k_norm3(float* __restrict__ Y,
                                               const unsigned char* __restrict__ mask,
                                               const float* __restrict__ ss) {
    const long n4 = (long)M_ * COUT / 4;
    const long t = (long)blockIdx.x * 256 + threadIdx.x;
    if (t >= n4) return;
    const long vox = t >> 4;
    const float4 y = ((const float4*)Y)[t];
    const int ch = (int)((t * 4) & 63);
    float4 o;
    if (mask[vox]) {
        o.x = fmaxf(fmaf(y.x, ss[ch],     ss[64 + ch]),     0.f);
        o.y = fmaxf(fmaf(y.y, ss[ch + 1], ss[64 + ch + 1]), 0.f);
        o.z = fmaxf(fmaf(y.z, ss[ch + 2], ss[64 + ch + 2]), 0.f);
        o.w = fmaxf(fmaf(y.w, ss[ch + 3], ss[64 + ch + 3]), 0.f);
    } else {
        o.x = o.y = o.z = o.w = 0.f;
    }
    ((float4*)Y)[t] = o;
}

extern "C" void kernel_launch(void* const* d_in, const int* in_sizes, int n_in,
                              void* d_out, int out_size, void* d_ws, size_t ws_size,
                              hipStream_t stream) {
    const float* feats = (const float*)d_in[0];
    const int*   coords = (const int*)d_in[1];
    const float* W1 = (const float*)d_in[2];
    const float* b1 = (const float*)d_in[3];
    const float* g1 = (const float*)d_in[4];
    const float* be1 = (const float*)d_in[5];
    const float* W2 = (const float*)d_in[6];
    const float* b2 = (const float*)d_in[7];
    const float* g2 = (const float*)d_in[8];
    const float* be2 = (const float*)d_in[9];
    const float* W3 = (const float*)d_in[10];
    const float* b3 = (const float*)d_in[11];
    const float* g3 = (const float*)d_in[12];
    const float* be3 = (const float*)d_in[13];
    float* out = (float*)d_out;

    char* ws = (char*)d_ws;
    const size_t gridBytes = (size_t)B_ * D_ * H_ * W_ * 4;   // 16,777,216
    const size_t bufBytes  = (size_t)N_ * CMID * 4;           // 19,200,000
    int*   grid = (int*)ws;
    float* bufA = (float*)(ws + gridBytes);
    float* bufB = (float*)(ws + gridBytes + bufBytes);
    unsigned char* mask = (unsigned char*)(ws + gridBytes + 2 * bufBytes);
    float* stats = (float*)(ws + gridBytes + 2 * bufBytes + (size_t)M_);

    float* st1 = stats;            // 32 sum + 32 sumsq
    float* st2 = stats + 64;
    float* st3 = stats + 128;      // 64 sum + 64 sumsq
    int*   nact = (int*)(stats + 256);
    float* ss1 = stats + 260;
    float* ss2 = stats + 324;
    float* ss3 = stats + 388;
    float* Wt1 = stats + 1024;                 // 27*512  floats
    float* Wt2 = Wt1 + 27 * 512;               // 27*1024 floats
    float* Wt3 = Wt2 + 27 * 1024;              // 27*2048 floats

    hipMemsetAsync(grid, 0xFF, gridBytes, stream);
    hipMemsetAsync(stats, 0, 260 * 4, stream);

    k_scatter<<<(N_ + 255) / 256, 256, 0, stream>>>(coords, grid);
    k_twist<<<(24192 + 255) / 256, 256, 0, stream>>>(W1, W2, W3, Wt1, Wt2, Wt3);

    const int nb_subm = 75000 / 4;   // 18750, exact (pairs, 4 waves/block)
    k_subm<CIN><<<nb_subm, 256, 0, stream>>>(feats, coords, grid, Wt1, b1, bufA, st1);
    k_finstats<CMID><<<1, 64, 0, stream>>>(st1, g1, be1, (float)N_, nullptr, ss1);
    k_norm<CMID><<<(N_ * CMID / 4 + 255) / 256, 256, 0, stream>>>(bufA, ss1, bufB,
                                                                  (long)N_ * CMID / 4);

    k_subm<CMID><<<nb_subm, 256, 0, stream>>>(bufB, coords, grid, Wt2, b2, bufA, st2);
    k_finstats<CMID><<<1, 64, 0, stream>>>(st2, g2, be2, (float)N_, nullptr, ss2);
    k_norm<CMID><<<(N_ * CMID / 4 + 255) / 256, 256, 0, stream>>>(bufA, ss2, bufB,
                                                                  (long)N_ * CMID / 4);

    k_down<<<NB_DOWN, 256, 0, stream>>>(bufB, grid, Wt3, b3, out, mask, st3, nact);
    k_finstats<COUT><<<1, 64, 0, stream>>>(st3, g3, be3, 0.f, nact, ss3);
    k_norm3<<<(M_ * COUT / 4) / 256, 256, 0, stream>>>(out, mask, ss3);
}

// Round 5
// 465.839 us; speedup vs baseline: 2.6148x; 2.6148x over previous
//
#include <hip/hip_runtime.h>

#define B_   2
#define D_   32
#define H_   256
#define W_   256
#define N_   150000
#define CIN  16
#define CMID 32
#define COUT 64
#define DO_  16
#define HO_  128
#define WO_  128
#define M_   (B_*DO_*HO_*WO_)   /* 524288 */
#define EPSf 1e-5f
#define NB_DOWN 8192             /* k_down blocks; %8==0, 64 voxels per block */

// ---------------- grid scatter ----------------
__global__ __launch_bounds__(256) void k_scatter(const int* __restrict__ coords,
                                                 int* __restrict__ grid) {
    int i = blockIdx.x * 256 + threadIdx.x;
    if (i >= N_) return;
    const int4 c = *(const int4*)(coords + 4 * (size_t)i);
    grid[((c.x * D_ + c.y) * H_ + c.z) * W_ + c.w] = i;
}

// ---------------- weight transpose ----------------
// Wt1[ki][(q*2+hi)*32+co][j] = W1[ki][hi*8 +q*4+j][co]   (q<2)
// Wt2[ki][(q*2+hi)*32+co][j] = W2[ki][hi*16+q*4+j][co]   (q<4)
// Wt3[ki][ q*64      +co][j] = W3[ki][      q*4+j][co]   (q<8, co<64)
__global__ __launch_bounds__(256) void k_twist(const float* __restrict__ W1,
                                               const float* __restrict__ W2,
                                               const float* __restrict__ W3,
                                               float* __restrict__ Wt1,
                                               float* __restrict__ Wt2,
                                               float* __restrict__ Wt3) {
    const int t = blockIdx.x * 256 + threadIdx.x;
    if (t < 3456) {
        const int ki = t / 128, r = t % 128;
        const int co = r & 31, qh = r >> 5, hi = qh & 1, q = qh >> 1;
        const float* src = W1 + ki * 512 + (hi * 8 + q * 4) * 32 + co;
        float4 o; o.x = src[0]; o.y = src[32]; o.z = src[64]; o.w = src[96];
        ((float4*)Wt1)[t] = o;
    } else if (t < 3456 + 6912) {
        const int u = t - 3456;
        const int ki = u / 256, r = u % 256;
        const int co = r & 31, qh = r >> 5, hi = qh & 1, q = qh >> 1;
        const float* src = W2 + ki * 1024 + (hi * 16 + q * 4) * 32 + co;
        float4 o; o.x = src[0]; o.y = src[32]; o.z = src[64]; o.w = src[96];
        ((float4*)Wt2)[u] = o;
    } else if (t < 3456 + 6912 + 13824) {
        const int u = t - 3456 - 6912;
        const int ki = u / 512, r = u % 512;
        const int co = r & 63, q = r >> 6;
        const float* src = W3 + ki * 2048 + q * 4 * 64 + co;
        float4 o; o.x = src[0]; o.y = src[64]; o.z = src[128]; o.w = src[192];
        ((float4*)Wt3)[u] = o;
    }
}

// ---------------- submanifold conv: one wave per POINT-PAIR ----------------
// (no fused stats -- per-block atomics at 18750 blocks saturate the atomic unit)
template <int CI>
__global__ __launch_bounds__(256) void k_subm(const float* __restrict__ X,
                                              const int* __restrict__ coords,
                                              const int* __restrict__ grid,
                                              const float* __restrict__ Wt,
                                              const float* __restrict__ bias,
                                              float* __restrict__ Y) {
    const int pid  = (blockIdx.x * 256 + threadIdx.x) >> 6;
    const int lane = threadIdx.x & 63;
    const int sub  = lane & 31;
    const int half = lane >> 5;
    const int iA   = pid * 2;

    const int4 cA = *(const int4*)(coords + 4 * (size_t)iA);
    const int4 cB = *(const int4*)(coords + 4 * (size_t)(iA + 1));
    const int4 cc = half ? cB : cA;

    int nidx = -1;
    if (sub < 27) {
        const int nz = cc.y + sub / 9 - 1;
        const int ny = cc.z + (sub / 3) % 3 - 1;
        const int nx = cc.w + sub % 3 - 1;
        if ((unsigned)nz < (unsigned)D_ && (unsigned)ny < (unsigned)H_ &&
            (unsigned)nx < (unsigned)W_)
            nidx = grid[((cc.x * D_ + nz) * H_ + ny) * W_ + nx];
    }
    const unsigned long long act = __ballot(nidx >= 0);
    unsigned int actA = (unsigned int)(act & 0x7FFFFFFull);
    unsigned int actB = (unsigned int)((act >> 32) & 0x7FFFFFFull);

    float accA = 0.f, accB = 0.f;

    while (actA | actB) {
        if (actA) {
            const int ki = __builtin_ctz(actA); actA &= actA - 1;
            const int ni = __shfl(nidx, ki, 64);
            const float* __restrict__ f = X + (size_t)ni * CI + half * (CI / 2);
            const float4* __restrict__ w4 =
                (const float4*)Wt + (size_t)ki * (CI * 8) + half * 32 + sub;
#pragma unroll
            for (int q = 0; q < CI / 8; ++q) {
                const float4 fv = *(const float4*)(f + q * 4);
                const float4 wv = w4[q * 64];
                accA = fmaf(fv.x, wv.x, accA);
                accA = fmaf(fv.y, wv.y, accA);
                accA = fmaf(fv.z, wv.z, accA);
                accA = fmaf(fv.w, wv.w, accA);
            }
        }
        if (actB) {
            const int ki = __builtin_ctz(actB); actB &= actB - 1;
            const int ni = __shfl(nidx, ki + 32, 64);
            const float* __restrict__ f = X + (size_t)ni * CI + half * (CI / 2);
            const float4* __restrict__ w4 =
                (const float4*)Wt + (size_t)ki * (CI * 8) + half * 32 + sub;
#pragma unroll
            for (int q = 0; q < CI / 8; ++q) {
                const float4 fv = *(const float4*)(f + q * 4);
                const float4 wv = w4[q * 64];
                accB = fmaf(fv.x, wv.x, accB);
                accB = fmaf(fv.y, wv.y, accB);
                accB = fmaf(fv.z, wv.z, accB);
                accB = fmaf(fv.w, wv.w, accB);
            }
        }
    }

    accA += __shfl_xor(accA, 32, 64);     // combine ci halves
    accB += __shfl_xor(accB, 32, 64);
    const float outv = (half ? accB : accA) + bias[sub];
    Y[(size_t)(iA + half) * 32 + sub] = outv;
}

// ---------------- strided down conv: LDS-staged grid rows -------------------
// Block = 64 consecutive output voxels (fixed bb,oz,oy; ox0..ox0+63). Their
// 27-tap neighborhoods span 9 contiguous grid rows x 129 cells -> stage into
// LDS once, probe from LDS (kills the scattered per-lane grid gathers).
__global__ __launch_bounds__(256) void k_down(const float* __restrict__ X,
                                              const int* __restrict__ grid,
                                              const float* __restrict__ Wt3,
                                              const float* __restrict__ bias,
                                              float* __restrict__ Y,
                                              unsigned char* __restrict__ mask,
                                              float* __restrict__ stats,
                                              int* __restrict__ nact) {
    const int b    = blockIdx.x;
    const int swz  = (b & 7) * (NB_DOWN / 8) + (b >> 3);
    const int tid  = threadIdx.x;
    const int wv   = tid >> 6;
    const int lane = tid & 63;
    const int sub  = lane & 31;
    const int half = lane >> 5;

    const int vox0 = swz * 64;
    const int ox0  = vox0 & 127;      // 0 or 64
    int t = vox0 >> 7;
    const int oy = t & 127; t >>= 7;
    const int oz = t & 15;
    const int bb = t >> 4;

    __shared__ int   gl[9][132];
    __shared__ float sd[256];
    __shared__ int   scnt[4];

    const int gx0 = 2 * ox0 - 1;
    for (int e = tid; e < 9 * 132; e += 256) {
        const int r  = e / 132, xo = e % 132;
        const int z  = 2 * oz - 1 + r / 3;
        const int y  = 2 * oy - 1 + r % 3;
        const int x  = gx0 + xo;
        int v = -1;
        if ((unsigned)z < (unsigned)D_ && (unsigned)y < (unsigned)H_ &&
            (unsigned)x < (unsigned)W_ && xo < 129)
            v = grid[((bb * D_ + z) * H_ + y) * W_ + x];
        gl[r][xo] = v;
    }
    __syncthreads();

    const int dz = sub / 9, dy = (sub / 3) % 3, dx = sub % 3;
    const int row = (sub < 27) ? dz * 3 + dy : 0;

    const float bv = bias[lane];
    float s = 0.f, s2 = 0.f;
    int cnt = 0;

    for (int it = 0; it < 8; ++it) {
        const int pr = wv * 8 + it;                 // pair index 0..31
        // lanes<32: voxel A (ox0+2pr), lanes>=32: voxel B (ox0+2pr+1)
        const int xo = 2 * (pr * 2 + half) + dx;    // 0..128
        const int nidx = (sub < 27) ? gl[row][xo] : -1;

        const unsigned long long act = __ballot(nidx >= 0);
        unsigned int actA = (unsigned int)(act & 0x7FFFFFFull);
        unsigned int actB = (unsigned int)((act >> 32) & 0x7FFFFFFull);
        const int mkA = actA ? 1 : 0;
        const int mkB = actB ? 1 : 0;

        float accA = 0.f, accB = 0.f;
        while (actA | actB) {
            if (actA) {
                const int ki = __builtin_ctz(actA); actA &= actA - 1;
                const int ni = __builtin_amdgcn_readfirstlane(__shfl(nidx, ki, 64));
                const float* __restrict__ fS = X + (size_t)ni * CMID;   // SGPR base
                const float4* __restrict__ w4 = (const float4*)Wt3 + (size_t)ki * 512 + lane;
#pragma unroll
                for (int q = 0; q < 8; ++q) {
                    const float4 wv4 = w4[q * 64];
                    accA = fmaf(fS[4 * q + 0], wv4.x, accA);
                    accA = fmaf(fS[4 * q + 1], wv4.y, accA);
                    accA = fmaf(fS[4 * q + 2], wv4.z, accA);
                    accA = fmaf(fS[4 * q + 3], wv4.w, accA);
                }
            }
            if (actB) {
                const int ki = __builtin_ctz(actB); actB &= actB - 1;
                const int ni = __builtin_amdgcn_readfirstlane(__shfl(nidx, ki + 32, 64));
                const float* __restrict__ fS = X + (size_t)ni * CMID;
                const float4* __restrict__ w4 = (const float4*)Wt3 + (size_t)ki * 512 + lane;
#pragma unroll
                for (int q = 0; q < 8; ++q) {
                    const float4 wv4 = w4[q * 64];
                    accB = fmaf(fS[4 * q + 0], wv4.x, accB);
                    accB = fmaf(fS[4 * q + 1], wv4.y, accB);
                    accB = fmaf(fS[4 * q + 2], wv4.z, accB);
                    accB = fmaf(fS[4 * q + 3], wv4.w, accB);
                }
            }
        }

        const int vA = vox0 + pr * 2;
        const float oA = mkA ? accA + bv : 0.f;
        const float oB = mkB ? accB + bv : 0.f;
        Y[(size_t)vA * COUT + lane]       = oA;
        Y[(size_t)(vA + 1) * COUT + lane] = oB;
        if (lane == 0) {
            mask[vA]     = (unsigned char)mkA;
            mask[vA + 1] = (unsigned char)mkB;
            cnt += mkA + mkB;
        }
        s  += oA + oB;
        s2 += oA * oA + oB * oB;
    }

    // fused stage-3 stats (8192 long-lived blocks: atomic rate is safe, R3-proven)
    sd[tid] = s;
    if (lane == 0) scnt[wv] = cnt;
    __syncthreads();
    if (tid < 64) atomicAdd(stats + tid, sd[tid] + sd[tid + 64] + sd[tid + 128] + sd[tid + 192]);
    __syncthreads();
    sd[tid] = s2;
    __syncthreads();
    if (tid < 64) atomicAdd(stats + 64 + tid, sd[tid] + sd[tid + 64] + sd[tid + 128] + sd[tid + 192]);
    if (tid == 0) atomicAdd(nact, scnt[0] + scnt[1] + scnt[2] + scnt[3]);
}

// ---------------- per-channel sum / sumsq (stages 1,2) ----------------
template <int C>
__global__ __launch_bounds__(256) void k_stats(const float* __restrict__ Y,
                                               long n_elems,
                                               float* __restrict__ stats) {
    __shared__ float sdata[256];
    const int t = threadIdx.x;
    const long stride = (long)gridDim.x * 256;
    float s = 0.f, s2 = 0.f;
    for (long idx = (long)blockIdx.x * 256 + t; idx < n_elems; idx += stride) {
        const float v = Y[idx];
        s += v; s2 += v * v;
    }
    sdata[t] = s; __syncthreads();
    for (int off = 128; off >= C; off >>= 1) {
        if (t < off) sdata[t] += sdata[t + off];
        __syncthreads();
    }
    if (t < C) atomicAdd(stats + t, sdata[t]);
    __syncthreads();
    sdata[t] = s2; __syncthreads();
    for (int off = 128; off >= C; off >>= 1) {
        if (t < off) sdata[t] += sdata[t + off];
        __syncthreads();
    }
    if (t < C) atomicAdd(stats + C + t, sdata[t]);
}

// ---------------- finalize scale/shift ----------------
template <int C>
__global__ void k_finstats(const float* __restrict__ stats,
                           const float* __restrict__ g,
                           const float* __restrict__ be,
                           float nfix, const int* __restrict__ nact,
                           float* __restrict__ ss) {
    const int c = threadIdx.x;
    if (c >= C) return;
    float n = nfix;
    if (nact) { int na = *nact; n = (float)(na > 0 ? na : 1); }
    const float m  = stats[c] / n;
    const float v  = stats[C + c] / n - m * m;
    const float sc = g[c] * rsqrtf(v + EPSf);
    ss[c]     = sc;
    ss[C + c] = be[c] - m * sc;
}

// ---------------- normalize (BN+ReLU) ----------------
template <int C>
__global__ __launch_bounds__(256) void k_norm(const float* __restrict__ Y,
                                              const float* __restrict__ ss,
                                              float* __restrict__ Xo, long n4) {
    const long t = (long)blockIdx.x * 256 + threadIdx.x;
    if (t >= n4) return;
    const float4 y = ((const float4*)Y)[t];
    const int ch = (int)((t * 4) % C);
    float4 o;
    o.x = fmaxf(fmaf(y.x, ss[ch],     ss[C + ch]),     0.f);
    o.y = fmaxf(fmaf(y.y, ss[ch + 1], ss[C + ch + 1]), 0.f);
    o.z = fmaxf(fmaf(y.z, ss[ch + 2], ss[C + ch + 2]), 0.f);
    o.w = fmaxf(fmaf(y.w, ss[ch + 3], ss[C + ch + 3]), 0.f);
    ((float4*)Xo)[t] = o;
}

__global__ __launch_bounds__(256) void k_norm3(float* __restrict__ Y,
                                               const unsigned char* __restrict__ mask,
                                               const float* __restrict__ ss) {
    const long n4 = (long)M_ * COUT / 4;
    const long t = (long)blockIdx.x * 256 + threadIdx.x;
    if (t >= n4) return;
    const long vox = t >> 4;
    const float4 y = ((const float4*)Y)[t];
    const int ch = (int)((t * 4) & 63);
    float4 o;
    if (mask[vox]) {
        o.x = fmaxf(fmaf(y.x, ss[ch],     ss[64 + ch]),     0.f);
        o.y = fmaxf(fmaf(y.y, ss[ch + 1], ss[64 + ch + 1]), 0.f);
        o.z = fmaxf(fmaf(y.z, ss[ch + 2], ss[64 + ch + 2]), 0.f);
        o.w = fmaxf(fmaf(y.w, ss[ch + 3], ss[64 + ch + 3]), 0.f);
    } else {
        o.x = o.y = o.z = o.w = 0.f;
    }
    ((float4*)Y)[t] = o;
}

extern "C" void kernel_launch(void* const* d_in, const int* in_sizes, int n_in,
                              void* d_out, int out_size, void* d_ws, size_t ws_size,
                              hipStream_t stream) {
    const float* feats = (const float*)d_in[0];
    const int*   coords = (const int*)d_in[1];
    const float* W1 = (const float*)d_in[2];
    const float* b1 = (const float*)d_in[3];
    const float* g1 = (const float*)d_in[4];
    const float* be1 = (const float*)d_in[5];
    const float* W2 = (const float*)d_in[6];
    const float* b2 = (const float*)d_in[7];
    const float* g2 = (const float*)d_in[8];
    const float* be2 = (const float*)d_in[9];
    const float* W3 = (const float*)d_in[10];
    const float* b3 = (const float*)d_in[11];
    const float* g3 = (const float*)d_in[12];
    const float* be3 = (const float*)d_in[13];
    float* out = (float*)d_out;

    char* ws = (char*)d_ws;
    const size_t gridBytes = (size_t)B_ * D_ * H_ * W_ * 4;   // 16,777,216
    const size_t bufBytes  = (size_t)N_ * CMID * 4;           // 19,200,000
    int*   grid = (int*)ws;
    float* bufA = (float*)(ws + gridBytes);
    float* bufB = (float*)(ws + gridBytes + bufBytes);
    unsigned char* mask = (unsigned char*)(ws + gridBytes + 2 * bufBytes);
    float* stats = (float*)(ws + gridBytes + 2 * bufBytes + (size_t)M_);

    float* st1 = stats;            // 32 sum + 32 sumsq
    float* st2 = stats + 64;
    float* st3 = stats + 128;      // 64 sum + 64 sumsq
    int*   nact = (int*)(stats + 256);
    float* ss1 = stats + 260;
    float* ss2 = stats + 324;
    float* ss3 = stats + 388;
    float* Wt1 = stats + 1024;                 // 27*512  floats
    float* Wt2 = Wt1 + 27 * 512;               // 27*1024 floats
    float* Wt3 = Wt2 + 27 * 1024;              // 27*2048 floats

    hipMemsetAsync(grid, 0xFF, gridBytes, stream);
    hipMemsetAsync(stats, 0, 260 * 4, stream);

    k_scatter<<<(N_ + 255) / 256, 256, 0, stream>>>(coords, grid);
    k_twist<<<(24192 + 255) / 256, 256, 0, stream>>>(W1, W2, W3, Wt1, Wt2, Wt3);

    const int nb_subm = 75000 / 4;   // 18750, exact (pairs, 4 waves/block)
    k_subm<CIN><<<nb_subm, 256, 0, stream>>>(feats, coords, grid, Wt1, b1, bufA);
    k_stats<CMID><<<512, 256, 0, stream>>>(bufA, (long)N_ * CMID, st1);
    k_finstats<CMID><<<1, 64, 0, stream>>>(st1, g1, be1, (float)N_, nullptr, ss1);
    k_norm<CMID><<<(N_ * CMID / 4 + 255) / 256, 256, 0, stream>>>(bufA, ss1, bufB,
                                                                  (long)N_ * CMID / 4);

    k_subm<CMID><<<nb_subm, 256, 0, stream>>>(bufB, coords, grid, Wt2, b2, bufA);
    k_stats<CMID><<<512, 256, 0, stream>>>(bufA, (long)N_ * CMID, st2);
    k_finstats<CMID><<<1, 64, 0, stream>>>(st2, g2, be2, (float)N_, nullptr, ss2);
    k_norm<CMID><<<(N_ * CMID / 4 + 255) / 256, 256, 0, stream>>>(bufA, ss2, bufB,
                                                                  (long)N_ * CMID / 4);

    k_down<<<NB_DOWN, 256, 0, stream>>>(bufB, grid, Wt3, b3, out, mask, st3, nact);
    k_finstats<COUT><<<1, 64, 0, stream>>>(st3, g3, be3, 0.f, nact, ss3);
    k_norm3<<<(M_ * COUT / 4) / 256, 256, 0, stream>>>(out, mask, ss3);
}

// Round 6
// 380.727 us; speedup vs baseline: 3.1993x; 1.2236x over previous
//
#include <hip/hip_runtime.h>

#define B_   2
#define D_   32
#define H_   256
#define W_   256
#define N_   150000
#define CIN  16
#define CMID 32
#define COUT 64
#define DO_  16
#define HO_  128
#define WO_  128
#define M_   (B_*DO_*HO_*WO_)   /* 524288 */
#define EPSf 1e-5f
#define NB_DOWN 8192             /* k_down blocks; %8==0, 64 voxels per block */
#define NREP 64                  /* stage-3 stats replicas (atomic de-contention) */

// ---------------- grid scatter ----------------
__global__ __launch_bounds__(256) void k_scatter(const int* __restrict__ coords,
                                                 int* __restrict__ grid) {
    int i = blockIdx.x * 256 + threadIdx.x;
    if (i >= N_) return;
    const int4 c = *(const int4*)(coords + 4 * (size_t)i);
    grid[((c.x * D_ + c.y) * H_ + c.z) * W_ + c.w] = i;
}

// ---------------- weight transpose ----------------
__global__ __launch_bounds__(256) void k_twist(const float* __restrict__ W1,
                                               const float* __restrict__ W2,
                                               const float* __restrict__ W3,
                                               float* __restrict__ Wt1,
                                               float* __restrict__ Wt2,
                                               float* __restrict__ Wt3) {
    const int t = blockIdx.x * 256 + threadIdx.x;
    if (t < 3456) {
        const int ki = t / 128, r = t % 128;
        const int co = r & 31, qh = r >> 5, hi = qh & 1, q = qh >> 1;
        const float* src = W1 + ki * 512 + (hi * 8 + q * 4) * 32 + co;
        float4 o; o.x = src[0]; o.y = src[32]; o.z = src[64]; o.w = src[96];
        ((float4*)Wt1)[t] = o;
    } else if (t < 3456 + 6912) {
        const int u = t - 3456;
        const int ki = u / 256, r = u % 256;
        const int co = r & 31, qh = r >> 5, hi = qh & 1, q = qh >> 1;
        const float* src = W2 + ki * 1024 + (hi * 16 + q * 4) * 32 + co;
        float4 o; o.x = src[0]; o.y = src[32]; o.z = src[64]; o.w = src[96];
        ((float4*)Wt2)[u] = o;
    } else if (t < 3456 + 6912 + 13824) {
        const int u = t - 3456 - 6912;
        const int ki = u / 512, r = u % 512;
        const int co = r & 63, q = r >> 6;
        const float* src = W3 + ki * 2048 + q * 4 * 64 + co;
        float4 o; o.x = src[0]; o.y = src[64]; o.z = src[128]; o.w = src[192];
        ((float4*)Wt3)[u] = o;
    }
}

// ---------------- submanifold conv: one wave per POINT-PAIR ----------------
template <int CI>
__global__ __launch_bounds__(256) void k_subm(const float* __restrict__ X,
                                              const int* __restrict__ coords,
                                              const int* __restrict__ grid,
                                              const float* __restrict__ Wt,
                                              const float* __restrict__ bias,
                                              float* __restrict__ Y) {
    const int pid  = (blockIdx.x * 256 + threadIdx.x) >> 6;
    const int lane = threadIdx.x & 63;
    const int sub  = lane & 31;
    const int half = lane >> 5;
    const int iA   = pid * 2;

    const int4 cA = *(const int4*)(coords + 4 * (size_t)iA);
    const int4 cB = *(const int4*)(coords + 4 * (size_t)(iA + 1));
    const int4 cc = half ? cB : cA;

    int nidx = -1;
    if (sub < 27) {
        const int nz = cc.y + sub / 9 - 1;
        const int ny = cc.z + (sub / 3) % 3 - 1;
        const int nx = cc.w + sub % 3 - 1;
        if ((unsigned)nz < (unsigned)D_ && (unsigned)ny < (unsigned)H_ &&
            (unsigned)nx < (unsigned)W_)
            nidx = grid[((cc.x * D_ + nz) * H_ + ny) * W_ + nx];
    }
    const unsigned long long act = __ballot(nidx >= 0);
    unsigned int actA = (unsigned int)(act & 0x7FFFFFFull);
    unsigned int actB = (unsigned int)((act >> 32) & 0x7FFFFFFull);

    float accA = 0.f, accB = 0.f;

    while (actA | actB) {
        if (actA) {
            const int ki = __builtin_ctz(actA); actA &= actA - 1;
            const int ni = __shfl(nidx, ki, 64);
            const float* __restrict__ f = X + (size_t)ni * CI + half * (CI / 2);
            const float4* __restrict__ w4 =
                (const float4*)Wt + (size_t)ki * (CI * 8) + half * 32 + sub;
#pragma unroll
            for (int q = 0; q < CI / 8; ++q) {
                const float4 fv = *(const float4*)(f + q * 4);
                const float4 wv = w4[q * 64];
                accA = fmaf(fv.x, wv.x, accA);
                accA = fmaf(fv.y, wv.y, accA);
                accA = fmaf(fv.z, wv.z, accA);
                accA = fmaf(fv.w, wv.w, accA);
            }
        }
        if (actB) {
            const int ki = __builtin_ctz(actB); actB &= actB - 1;
            const int ni = __shfl(nidx, ki + 32, 64);
            const float* __restrict__ f = X + (size_t)ni * CI + half * (CI / 2);
            const float4* __restrict__ w4 =
                (const float4*)Wt + (size_t)ki * (CI * 8) + half * 32 + sub;
#pragma unroll
            for (int q = 0; q < CI / 8; ++q) {
                const float4 fv = *(const float4*)(f + q * 4);
                const float4 wv = w4[q * 64];
                accB = fmaf(fv.x, wv.x, accB);
                accB = fmaf(fv.y, wv.y, accB);
                accB = fmaf(fv.z, wv.z, accB);
                accB = fmaf(fv.w, wv.w, accB);
            }
        }
    }

    accA += __shfl_xor(accA, 32, 64);     // combine ci halves
    accB += __shfl_xor(accB, 32, 64);
    const float outv = (half ? accB : accA) + bias[sub];
    Y[(size_t)(iA + half) * 32 + sub] = outv;
}

// ---------------- strided down conv: LDS-staged grid rows -------------------
// Stage-3 stats fused, but accumulated into one of NREP replicated slabs
// (slab = blockIdx & 63) so same-line atomic contention is ~4k updates/line
// instead of ~262k (the R5 230us floor was TCC atomic serialization).
__global__ __launch_bounds__(256) void k_down(const float* __restrict__ X,
                                              const int* __restrict__ grid,
                                              const float* __restrict__ Wt3,
                                              const float* __restrict__ bias,
                                              float* __restrict__ Y,
                                              unsigned char* __restrict__ mask,
                                              float* __restrict__ slab0,
                                              int* __restrict__ nacts) {
    const int b    = blockIdx.x;
    const int swz  = (b & 7) * (NB_DOWN / 8) + (b >> 3);
    const int tid  = threadIdx.x;
    const int wv   = tid >> 6;
    const int lane = tid & 63;
    const int sub  = lane & 31;
    const int half = lane >> 5;

    const int vox0 = swz * 64;
    const int ox0  = vox0 & 127;      // 0 or 64
    int t = vox0 >> 7;
    const int oy = t & 127; t >>= 7;
    const int oz = t & 15;
    const int bb = t >> 4;

    __shared__ int   gl[9][132];
    __shared__ float sd[256];
    __shared__ int   scnt[4];

    const int gx0 = 2 * ox0 - 1;
    for (int e = tid; e < 9 * 132; e += 256) {
        const int r  = e / 132, xo = e % 132;
        const int z  = 2 * oz - 1 + r / 3;
        const int y  = 2 * oy - 1 + r % 3;
        const int x  = gx0 + xo;
        int v = -1;
        if ((unsigned)z < (unsigned)D_ && (unsigned)y < (unsigned)H_ &&
            (unsigned)x < (unsigned)W_ && xo < 129)
            v = grid[((bb * D_ + z) * H_ + y) * W_ + x];
        gl[r][xo] = v;
    }
    __syncthreads();

    const int dz = sub / 9, dy = (sub / 3) % 3, dx = sub % 3;
    const int row = (sub < 27) ? dz * 3 + dy : 0;

    const float bv = bias[lane];
    float s = 0.f, s2 = 0.f;
    int cnt = 0;

    for (int it = 0; it < 8; ++it) {
        const int pr = wv * 8 + it;                 // pair index 0..31
        const int xo = 2 * (pr * 2 + half) + dx;    // 0..128
        const int nidx = (sub < 27) ? gl[row][xo] : -1;

        const unsigned long long act = __ballot(nidx >= 0);
        unsigned int actA = (unsigned int)(act & 0x7FFFFFFull);
        unsigned int actB = (unsigned int)((act >> 32) & 0x7FFFFFFull);
        const int mkA = actA ? 1 : 0;
        const int mkB = actB ? 1 : 0;

        float accA = 0.f, accB = 0.f;
        while (actA | actB) {
            if (actA) {
                const int ki = __builtin_ctz(actA); actA &= actA - 1;
                const int ni = __builtin_amdgcn_readfirstlane(__shfl(nidx, ki, 64));
                const float* __restrict__ fS = X + (size_t)ni * CMID;   // SGPR base
                const float4* __restrict__ w4 = (const float4*)Wt3 + (size_t)ki * 512 + lane;
#pragma unroll
                for (int q = 0; q < 8; ++q) {
                    const float4 wv4 = w4[q * 64];
                    accA = fmaf(fS[4 * q + 0], wv4.x, accA);
                    accA = fmaf(fS[4 * q + 1], wv4.y, accA);
                    accA = fmaf(fS[4 * q + 2], wv4.z, accA);
                    accA = fmaf(fS[4 * q + 3], wv4.w, accA);
                }
            }
            if (actB) {
                const int ki = __builtin_ctz(actB); actB &= actB - 1;
                const int ni = __builtin_amdgcn_readfirstlane(__shfl(nidx, ki + 32, 64));
                const float* __restrict__ fS = X + (size_t)ni * CMID;
                const float4* __restrict__ w4 = (const float4*)Wt3 + (size_t)ki * 512 + lane;
#pragma unroll
                for (int q = 0; q < 8; ++q) {
                    const float4 wv4 = w4[q * 64];
                    accB = fmaf(fS[4 * q + 0], wv4.x, accB);
                    accB = fmaf(fS[4 * q + 1], wv4.y, accB);
                    accB = fmaf(fS[4 * q + 2], wv4.z, accB);
                    accB = fmaf(fS[4 * q + 3], wv4.w, accB);
                }
            }
        }

        const int vA = vox0 + pr * 2;
        const float oA = mkA ? accA + bv : 0.f;
        const float oB = mkB ? accB + bv : 0.f;
        Y[(size_t)vA * COUT + lane]       = oA;
        Y[(size_t)(vA + 1) * COUT + lane] = oB;
        if (lane == 0) {
            mask[vA]     = (unsigned char)mkA;
            mask[vA + 1] = (unsigned char)mkB;
            cnt += mkA + mkB;
        }
        s  += oA + oB;
        s2 += oA * oA + oB * oB;
    }

    float* __restrict__ slab = slab0 + (size_t)(b & (NREP - 1)) * 128;
    sd[tid] = s;
    if (lane == 0) scnt[wv] = cnt;
    __syncthreads();
    if (tid < 64) atomicAdd(slab + tid, sd[tid] + sd[tid + 64] + sd[tid + 128] + sd[tid + 192]);
    __syncthreads();
    sd[tid] = s2;
    __syncthreads();
    if (tid < 64) atomicAdd(slab + 64 + tid, sd[tid] + sd[tid + 64] + sd[tid + 128] + sd[tid + 192]);
    if (tid == 0) atomicAdd(nacts + (b & (NREP - 1)), scnt[0] + scnt[1] + scnt[2] + scnt[3]);
}

// ---------------- per-channel sum / sumsq (stages 1,2) ----------------
template <int C>
__global__ __launch_bounds__(256) void k_stats(const float* __restrict__ Y,
                                               long n_elems,
                                               float* __restrict__ stats) {
    __shared__ float sdata[256];
    const int t = threadIdx.x;
    const long stride = (long)gridDim.x * 256;
    float s = 0.f, s2 = 0.f;
    for (long idx = (long)blockIdx.x * 256 + t; idx < n_elems; idx += stride) {
        const float v = Y[idx];
        s += v; s2 += v * v;
    }
    sdata[t] = s; __syncthreads();
    for (int off = 128; off >= C; off >>= 1) {
        if (t < off) sdata[t] += sdata[t + off];
        __syncthreads();
    }
    if (t < C) atomicAdd(stats + t, sdata[t]);
    __syncthreads();
    sdata[t] = s2; __syncthreads();
    for (int off = 128; off >= C; off >>= 1) {
        if (t < off) sdata[t] += sdata[t + off];
        __syncthreads();
    }
    if (t < C) atomicAdd(stats + C + t, sdata[t]);
}

// ---------------- finalize scale/shift (stages 1,2) ----------------
template <int C>
__global__ void k_finstats(const float* __restrict__ stats,
                           const float* __restrict__ g,
                           const float* __restrict__ be,
                           float nfix,
                           float* __restrict__ ss) {
    const int c = threadIdx.x;
    if (c >= C) return;
    const float n  = nfix;
    const float m  = stats[c] / n;
    const float v  = stats[C + c] / n - m * m;
    const float sc = g[c] * rsqrtf(v + EPSf);
    ss[c]     = sc;
    ss[C + c] = be[c] - m * sc;
}

// ---------------- finalize scale/shift (stage 3, folds NREP replicas) -------
__global__ void k_finstats3(const float* __restrict__ slab0,
                            const int* __restrict__ nacts,
                            const float* __restrict__ g,
                            const float* __restrict__ be,
                            float* __restrict__ ss) {
    const int c = threadIdx.x;   // 64 threads
    if (c >= 64) return;
    float sm = 0.f, s2 = 0.f;
    int na = 0;
    for (int r = 0; r < NREP; ++r) {
        sm += slab0[r * 128 + c];
        s2 += slab0[r * 128 + 64 + c];
        na += nacts[r];
    }
    const float n  = (float)(na > 0 ? na : 1);
    const float m  = sm / n;
    const float v  = s2 / n - m * m;
    const float sc = g[c] * rsqrtf(v + EPSf);
    ss[c]      = sc;
    ss[64 + c] = be[c] - m * sc;
}

// ---------------- normalize (BN+ReLU) ----------------
template <int C>
__global__ __launch_bounds__(256) void k_norm(const float* __restrict__ Y,
                                              const float* __restrict__ ss,
                                              float* __restrict__ Xo, long n4) {
    const long t = (long)blockIdx.x * 256 + threadIdx.x;
    if (t >= n4) return;
    const float4 y = ((const float4*)Y)[t];
    const int ch = (int)((t * 4) % C);
    float4 o;
    o.x = fmaxf(fmaf(y.x, ss[ch],     ss[C + ch]),     0.f);
    o.y = fmaxf(fmaf(y.y, ss[ch + 1], ss[C + ch + 1]), 0.f);
    o.z = fmaxf(fmaf(y.z, ss[ch + 2], ss[C + ch + 2]), 0.f);
    o.w = fmaxf(fmaf(y.w, ss[ch + 3], ss[C + ch + 3]), 0.f);
    ((float4*)Xo)[t] = o;
}

__global__ __launch_bounds__(256) void k_norm3(float* __restrict__ Y,
                                               const unsigned char* __restrict__ mask,
                                               const float* __restrict__ ss) {
    const long n4 = (long)M_ * COUT / 4;
    const long t = (long)blockIdx.x * 256 + threadIdx.x;
    if (t >= n4) return;
    const long vox = t >> 4;
    const float4 y = ((const float4*)Y)[t];
    const int ch = (int)((t * 4) & 63);
    float4 o;
    if (mask[vox]) {
        o.x = fmaxf(fmaf(y.x, ss[ch],     ss[64 + ch]),     0.f);
        o.y = fmaxf(fmaf(y.y, ss[ch + 1], ss[64 + ch + 1]), 0.f);
        o.z = fmaxf(fmaf(y.z, ss[ch + 2], ss[64 + ch + 2]), 0.f);
        o.w = fmaxf(fmaf(y.w, ss[ch + 3], ss[64 + ch + 3]), 0.f);
    } else {
        o.x = o.y = o.z = o.w = 0.f;
    }
    ((float4*)Y)[t] = o;
}

extern "C" void kernel_launch(void* const* d_in, const int* in_sizes, int n_in,
                              void* d_out, int out_size, void* d_ws, size_t ws_size,
                              hipStream_t stream) {
    const float* feats = (const float*)d_in[0];
    const int*   coords = (const int*)d_in[1];
    const float* W1 = (const float*)d_in[2];
    const float* b1 = (const float*)d_in[3];
    const float* g1 = (const float*)d_in[4];
    const float* be1 = (const float*)d_in[5];
    const float* W2 = (const float*)d_in[6];
    const float* b2 = (const float*)d_in[7];
    const float* g2 = (const float*)d_in[8];
    const float* be2 = (const float*)d_in[9];
    const float* W3 = (const float*)d_in[10];
    const float* b3 = (const float*)d_in[11];
    const float* g3 = (const float*)d_in[12];
    const float* be3 = (const float*)d_in[13];
    float* out = (float*)d_out;

    char* ws = (char*)d_ws;
    const size_t gridBytes = (size_t)B_ * D_ * H_ * W_ * 4;   // 16,777,216
    const size_t bufBytes  = (size_t)N_ * CMID * 4;           // 19,200,000
    int*   grid = (int*)ws;
    float* bufA = (float*)(ws + gridBytes);
    float* bufB = (float*)(ws + gridBytes + bufBytes);
    unsigned char* mask = (unsigned char*)(ws + gridBytes + 2 * bufBytes);
    float* stats = (float*)(ws + gridBytes + 2 * bufBytes + (size_t)M_);

    float* st1   = stats;                 // 32 sum + 32 sumsq
    float* st2   = stats + 64;            // 32 sum + 32 sumsq
    float* ss1   = stats + 260;
    float* ss2   = stats + 324;
    float* ss3   = stats + 388;
    float* slab3 = stats + 1024;          // NREP x 128 floats
    int*   nacts = (int*)(stats + 1024 + NREP * 128);   // NREP ints
    float* Wt1 = stats + 16384;                // 27*512  floats
    float* Wt2 = Wt1 + 27 * 512;               // 27*1024 floats
    float* Wt3 = Wt2 + 27 * 1024;              // 27*2048 floats

    hipMemsetAsync(grid, 0xFF, gridBytes, stream);
    hipMemsetAsync(stats, 0, (1024 + NREP * 128 + NREP) * 4, stream);

    k_scatter<<<(N_ + 255) / 256, 256, 0, stream>>>(coords, grid);
    k_twist<<<(24192 + 255) / 256, 256, 0, stream>>>(W1, W2, W3, Wt1, Wt2, Wt3);

    const int nb_subm = 75000 / 4;   // 18750, exact (pairs, 4 waves/block)
    k_subm<CIN><<<nb_subm, 256, 0, stream>>>(feats, coords, grid, Wt1, b1, bufA);
    k_stats<CMID><<<512, 256, 0, stream>>>(bufA, (long)N_ * CMID, st1);
    k_finstats<CMID><<<1, 64, 0, stream>>>(st1, g1, be1, (float)N_, ss1);
    k_norm<CMID><<<(N_ * CMID / 4 + 255) / 256, 256, 0, stream>>>(bufA, ss1, bufB,
                                                                  (long)N_ * CMID / 4);

    k_subm<CMID><<<nb_subm, 256, 0, stream>>>(bufB, coords, grid, Wt2, b2, bufA);
    k_stats<CMID><<<512, 256, 0, stream>>>(bufA, (long)N_ * CMID, st2);
    k_finstats<CMID><<<1, 64, 0, stream>>>(st2, g2, be2, (float)N_, ss2);
    k_norm<CMID><<<(N_ * CMID / 4 + 255) / 256, 256, 0, stream>>>(bufA, ss2, bufB,
                                                                  (long)N_ * CMID / 4);

    k_down<<<NB_DOWN, 256, 0, stream>>>(bufB, grid, Wt3, b3, out, mask, slab3, nacts);
    k_finstats3<<<1, 64, 0, stream>>>(slab3, nacts, g3, be3, ss3);
    k_norm3<<<(M_ * COUT / 4) / 256, 256, 0, stream>>>(out, mask, ss3);
}